// Round 1
// baseline (949.692 us; speedup 1.0000x reference)
//
#include <hip/hip_runtime.h>
#include <cmath>

// Problem constants (from reference)
#define BB   512                 // graphs
#define NN   246                 // nodes per graph per type
#define DD   256                 // feature dim
#define DEGC 32                  // edges per node
#define KK   197                 // kept nodes per graph (ceil(0.8*246))
#define NTOT (BB*NN)             // 125952
#define EE   (BB*NN*DEGC)        // 4030464 edges per edge type
#define EPG  (NN*DEGC)           // 7872 edges per graph
#define EPG4 (EPG/4)             // 1968
#define BKK  (BB*KK)             // 100864

// d_out element offsets (float32, concatenated reference outputs)
// xb[BK,D], xd[BK,D], {ei_f[2E], valid[E]} x4 (bb,bd,db,dd),
// batch_b[BK], batch_d[BK], perm_b[BK], perm_d[BK], s_bold[NT], s_dti[NT]
#define O_XB     0LL
#define O_XD     25821184LL
#define O_E0     51642368LL
#define STRIDE3E 12091392LL      // 3*EE per edge-type block
#define O_BATCHB 100007936LL
#define O_BATCHD 100108800LL
#define O_PERMB  100209664LL
#define O_PERMD  100310528LL
#define O_SB     100411392LL
#define O_SD     100537344LL
// total out elements = 100663296

// ---- order-preserving float<->uint encoding for atomicMax on floats ----
__device__ __forceinline__ unsigned f2o(float f) {
    unsigned u = __float_as_uint(f);
    return (u & 0x80000000u) ? ~u : (u | 0x80000000u);
}
__device__ __forceinline__ float o2f(unsigned u) {
    return (u & 0x80000000u) ? __uint_as_float(u & 0x7fffffffu)
                             : __uint_as_float(~u);
}

// ============ 1. projection: h = x @ w + b  (scalar per node) ============
// one wave per node; 64 lanes x float4 = 256 floats; double accumulate
__global__ __launch_bounds__(256) void proj_kernel(
    const float* __restrict__ xb, const float* __restrict__ xd,
    const float* __restrict__ wb, const float* __restrict__ bbp,
    const float* __restrict__ wd, const float* __restrict__ bdp,
    float* __restrict__ hb, float* __restrict__ hd) {
    int wid  = (blockIdx.x * 256 + threadIdx.x) >> 6;
    int lane = threadIdx.x & 63;
    if (wid >= 2 * NTOT) return;
    const float* x; const float* w; const float* bp; float* h; int node;
    if (wid < NTOT) { x = xb; w = wb; bp = bbp; h = hb; node = wid; }
    else            { x = xd; w = wd; bp = bdp; h = hd; node = wid - NTOT; }
    float4 xv = ((const float4*)(x + (long long)node * DD))[lane];
    float4 wv = ((const float4*)w)[lane];
    double acc = (double)xv.x * wv.x + (double)xv.y * wv.y +
                 (double)xv.z * wv.z + (double)xv.w * wv.w;
#pragma unroll
    for (int m = 32; m; m >>= 1) acc += __shfl_xor(acc, m, 64);
    if (lane == 0) h[node] = __fadd_rn((float)acc, bp[0]);
}

// ============ 2. per-(graph, edge-type) attention, fully in LDS ==========
// logit = leaky_relu(a_src*h_src[row] + a_dst*h_dst[col])
// segment softmax over col; out[c] = relu( sum(h_src*e) / (sum(e)+1e-16) )
__global__ __launch_bounds__(1024) void att_kernel(
    const int* __restrict__ ei_bb, const int* __restrict__ ei_bd,
    const int* __restrict__ ei_db, const int* __restrict__ ei_dd,
    const float* __restrict__ hb, const float* __restrict__ hd,
    const float* __restrict__ att, float* __restrict__ o) {
    __shared__ float          l_sh[EPG];     // per-edge logit
    __shared__ unsigned char  r_sh[EPG];     // row - base (0..245)
    __shared__ unsigned char  c_sh[EPG];     // col - base
    __shared__ unsigned       m_sh[NN];      // encoded max
    __shared__ float          s_sh[NN];      // sum(e)
    __shared__ float          num_sh[NN];    // sum(h_src*e)

    int bid = blockIdx.x;
    int t   = bid >> 9;          // edge type 0..3 (bb, bd, db, dd)
    int g   = bid & 511;         // graph
    const int* ei = (t == 0) ? ei_bb : (t == 1) ? ei_bd : (t == 2) ? ei_db : ei_dd;
    const float* hs  = (t >= 2) ? hd : hb;   // src: bb,bd from bold; db,dd from dti
    const float* hdt = (t & 1)  ? hd : hb;   // dst: bd,dd to dti
    float a_src = att[2 * t], a_dst = att[2 * t + 1];
    int base = g * NN;
    int tid  = threadIdx.x;

    if (tid < NN) { m_sh[tid] = 0u; s_sh[tid] = 0.f; num_sh[tid] = 0.f; }
    __syncthreads();

    const int4* rows = (const int4*)(ei + g * EPG);
    const int4* cols = (const int4*)(ei + EE + g * EPG);

    // phase 1: logits + segment max
    for (int q = tid; q < EPG4; q += 1024) {
        int4 r4 = rows[q], c4 = cols[q];
#pragma unroll
        for (int j = 0; j < 4; ++j) {
            int r = ((const int*)&r4)[j] - base;
            int c = ((const int*)&c4)[j] - base;
            float st = __fmul_rn(a_src, hs[base + r]);
            float dt = __fmul_rn(a_dst, hdt[base + c]);
            float l  = __fadd_rn(st, dt);
            l = (l >= 0.f) ? l : __fmul_rn(0.2f, l);   // leaky_relu 0.2
            int idx = q * 4 + j;
            l_sh[idx] = l;
            r_sh[idx] = (unsigned char)r;
            c_sh[idx] = (unsigned char)c;
            atomicMax(&m_sh[c], f2o(l));
        }
    }
    __syncthreads();

    // phase 2: exp + segment sums (LDS float atomics, native ds_add_f32)
    for (int idx = tid; idx < EPG; idx += 1024) {
        float l  = l_sh[idx];
        int   r  = r_sh[idx], c = c_sh[idx];
        float mx = o2f(m_sh[c]);
        float e  = expf(l - mx);
        atomicAdd(&s_sh[c], e);
        atomicAdd(&num_sh[c], __fmul_rn(hs[base + r], e));
    }
    __syncthreads();

    // phase 3: normalize + relu
    if (tid < NN) {
        float s = s_sh[tid] + 1e-16f;
        float v = num_sh[tid] / s;
        o[(long long)t * NTOT + base + tid] = (v > 0.f) ? v : 0.f;
    }
}

// ============ 3a. zero the 4 group-mean accumulators =====================
__global__ void zero_sums_kernel(double* sums) {
    if (threadIdx.x < 4 && blockIdx.x == 0) sums[threadIdx.x] = 0.0;
}

// ============ 3b. mean over NT of tanh(o*kw + kb), per edge type =========
__global__ __launch_bounds__(256) void grp_reduce_kernel(
    const float* __restrict__ o, const float* __restrict__ kwp,
    const float* __restrict__ kbp, double* __restrict__ sums) {
    int i = blockIdx.x * 256 + threadIdx.x;     // grid = 4*NT/256 = 1968
    int t = blockIdx.x / 492;                   // NT/256 = 492 blocks per type
    float kw = kwp[0], kb = kbp[0];
    float v = tanhf(__fadd_rn(__fmul_rn(o[i], kw), kb));
    double acc = (double)v;
#pragma unroll
    for (int m = 32; m; m >>= 1) acc += __shfl_xor(acc, m, 64);
    __shared__ double part[4];
    int lane = threadIdx.x & 63, wv = threadIdx.x >> 6;
    if (lane == 0) part[wv] = acc;
    __syncthreads();
    if (threadIdx.x == 0) {
        double tot = ((part[0] + part[1]) + part[2]) + part[3];
        atomicAdd(&sums[t], tot);
    }
}

// ============ 3c. semantic-attention weights (2-way softmax x 2) =========
__global__ void grp_w_kernel(const double* __restrict__ sums,
                             const float* __restrict__ qp,
                             float* __restrict__ wscal) {
    if (threadIdx.x == 0 && blockIdx.x == 0) {
        float q = qp[0];
        float tv[4];
#pragma unroll
        for (int i = 0; i < 4; ++i) tv[i] = (float)(sums[i] / (double)NTOT);
        // bold group: (o_bb = t0, o_db = t2)
        {
            float l0 = __fmul_rn(q, tv[0]), l1 = __fmul_rn(q, tv[2]);
            float mx = fmaxf(l0, l1);
            float e0 = expf(l0 - mx), e1 = expf(l1 - mx);
            float se = __fadd_rn(e0, e1);
            wscal[0] = e0 / se; wscal[1] = e1 / se;
        }
        // dti group: (o_bd = t1, o_dd = t3)
        {
            float l0 = __fmul_rn(q, tv[1]), l1 = __fmul_rn(q, tv[3]);
            float mx = fmaxf(l0, l1);
            float e0 = expf(l0 - mx), e1 = expf(l1 - mx);
            float se = __fadd_rn(e0, e1);
            wscal[2] = e0 / se; wscal[3] = e1 / se;
        }
    }
}

// ============ 3d. final scores; also written straight to d_out ===========
__global__ __launch_bounds__(256) void score_kernel(
    const float* __restrict__ o, const float* __restrict__ wscal,
    float* __restrict__ sb, float* __restrict__ sd,
    float* __restrict__ osb, float* __restrict__ osd) {
    int i = blockIdx.x * 256 + threadIdx.x;     // grid covers NT exactly
    float w0 = wscal[0], w1 = wscal[1], w2 = wscal[2], w3 = wscal[3];
    float vb = __fadd_rn(__fmul_rn(w0, o[i]),          __fmul_rn(w1, o[2LL * NTOT + i]));
    float vd = __fadd_rn(__fmul_rn(w2, o[NTOT + i]),   __fmul_rn(w3, o[3LL * NTOT + i]));
    sb[i] = vb; sd[i] = vd; osb[i] = vb; osd[i] = vd;
}

// ============ 4. per-graph top-K via bitonic sort (value desc, idx asc) ==
// replicates jax.lax.top_k incl. lower-index-first tie-break
__global__ __launch_bounds__(256) void topk_kernel(
    const float* __restrict__ sb, const float* __restrict__ sd,
    const int* __restrict__ batch_b, const int* __restrict__ batch_d,
    int* __restrict__ mask_b, int* __restrict__ mask_d,
    int* __restrict__ perm_b, int* __restrict__ perm_d,
    float* __restrict__ out) {
    __shared__ float v[256];
    __shared__ int   ix[256];
    int g = blockIdx.x, tid = threadIdx.x;
    for (int which = 0; which < 2; ++which) {
        const float* s     = which ? sd : sb;
        const int*   batch = which ? batch_d : batch_b;
        int* mask  = which ? mask_d : mask_b;
        int* permi = which ? perm_d : perm_b;
        float* operm  = out + (which ? O_PERMD : O_PERMB);
        float* obatch = out + (which ? O_BATCHD : O_BATCHB);
        v[tid]  = (tid < NN) ? s[g * NN + tid] : -INFINITY;
        ix[tid] = tid;
        __syncthreads();
        for (int k2 = 2; k2 <= 256; k2 <<= 1) {
            for (int j = k2 >> 1; j > 0; j >>= 1) {
                int p = tid ^ j;
                if (p > tid) {
                    float va = v[tid], vb2 = v[p];
                    int   ia = ix[tid], ib = ix[p];
                    bool before = (va > vb2) || (va == vb2 && ia < ib);
                    bool up = ((tid & k2) == 0);
                    if (up ? !before : before) {
                        v[tid] = vb2; v[p] = va; ix[tid] = ib; ix[p] = ia;
                    }
                }
                __syncthreads();
            }
        }
        if (tid < NN) {
            int node  = ix[tid];
            int gnode = g * NN + node;
            if (tid < KK) {
                int gp = g * KK + tid;
                permi[gp]  = gnode;
                operm[gp]  = (float)gnode;
                obatch[gp] = (float)batch[gnode];
                mask[gnode] = gp;
            } else {
                mask[gnode] = -1;
            }
        }
        __syncthreads();
    }
}

// ============ 5. gather kept rows, scale by tanh(score) ==================
__global__ __launch_bounds__(256) void gather_kernel(
    const float* __restrict__ xb, const float* __restrict__ xd,
    const int* __restrict__ perm_b, const int* __restrict__ perm_d,
    const float* __restrict__ sb, const float* __restrict__ sd,
    float* __restrict__ out) {
    int wid  = (blockIdx.x * 256 + threadIdx.x) >> 6;
    int lane = threadIdx.x & 63;
    if (wid >= 2 * BKK) return;
    int which = wid >= BKK;
    int j = which ? wid - BKK : wid;
    const float* x    = which ? xd : xb;
    const int*   perm = which ? perm_d : perm_b;
    const float* s    = which ? sd : sb;
    long long obase   = which ? O_XD : O_XB;
    int p = perm[j];
    float scale = tanhf(s[p]);
    float4 vv = ((const float4*)(x + (long long)p * DD))[lane];
    float4 r  = make_float4(vv.x * scale, vv.y * scale, vv.z * scale, vv.w * scale);
    ((float4*)(out + obase + (long long)j * DD))[lane] = r;
}

// ============ 6. edge filtering through the pooling masks ================
__global__ __launch_bounds__(256) void filter_kernel(
    const int* __restrict__ ei_bb, const int* __restrict__ ei_bd,
    const int* __restrict__ ei_db, const int* __restrict__ ei_dd,
    const int* __restrict__ mask_b, const int* __restrict__ mask_d,
    float* __restrict__ out) {
    const int QE = EE / 4;
    int tid = blockIdx.x * 256 + threadIdx.x;
    if (tid >= 4 * QE) return;
    int t = tid / QE;
    int q = tid - t * QE;
    const int* ei = (t == 0) ? ei_bb : (t == 1) ? ei_bd : (t == 2) ? ei_db : ei_dd;
    const int* mr = (t >= 2) ? mask_d : mask_b;  // bb:(mb,mb) bd:(mb,md) db:(md,mb) dd:(md,md)
    const int* mc = (t & 1)  ? mask_d : mask_b;
    int4 r4 = ((const int4*)ei)[q];
    int4 c4 = ((const int4*)(ei + EE))[q];
    float4 orow, ocol, oval;
#pragma unroll
    for (int j = 0; j < 4; ++j) {
        int r = mr[((const int*)&r4)[j]];
        int c = mc[((const int*)&c4)[j]];
        bool val = (r >= 0) && (c >= 0);
        ((float*)&orow)[j] = val ? (float)r : -1.f;
        ((float*)&ocol)[j] = val ? (float)c : -1.f;
        ((float*)&oval)[j] = val ? 1.f : 0.f;
    }
    float* base = out + O_E0 + (long long)t * STRIDE3E;
    ((float4*)base)[q]              = orow;
    ((float4*)(base + EE))[q]       = ocol;
    ((float4*)(base + 2LL * EE))[q] = oval;
}

// ========================== launcher =====================================
extern "C" void kernel_launch(void* const* d_in, const int* in_sizes, int n_in,
                              void* d_out, int out_size, void* d_ws, size_t ws_size,
                              hipStream_t stream) {
    const float* x_bold = (const float*)d_in[0];
    const float* x_dti  = (const float*)d_in[1];
    const float* pw_b   = (const float*)d_in[2];
    const float* pb_b   = (const float*)d_in[3];
    const float* pw_d   = (const float*)d_in[4];
    const float* pb_d   = (const float*)d_in[5];
    const float* att    = (const float*)d_in[6];
    const float* k_w    = (const float*)d_in[7];
    const float* k_b    = (const float*)d_in[8];
    const float* qv     = (const float*)d_in[9];
    const int* ei_bb    = (const int*)d_in[10];
    const int* ei_bd    = (const int*)d_in[11];
    const int* ei_db    = (const int*)d_in[12];
    const int* ei_dd    = (const int*)d_in[13];
    const int* batch_b  = (const int*)d_in[14];
    const int* batch_d  = (const int*)d_in[15];
    float* out = (float*)d_out;

    // workspace layout (~5.9 MB)
    char* w = (char*)d_ws;
    double* sums  = (double*)w;                       // 4 dbl
    float*  wscal = (float*)(w + 32);                 // 4 f32
    float*  hb    = (float*)(w + 48);                 // NT
    float*  hd    = hb + NTOT;                        // NT
    float*  obuf  = hd + NTOT;                        // 4*NT
    float*  sb    = obuf + 4LL * NTOT;                // NT
    float*  sd    = sb + NTOT;                        // NT
    int* mask_b   = (int*)(sd + NTOT);                // NT
    int* mask_d   = mask_b + NTOT;                    // NT
    int* perm_b   = mask_d + NTOT;                    // BK
    int* perm_d   = perm_b + BKK;                     // BK

    zero_sums_kernel<<<1, 64, 0, stream>>>(sums);
    proj_kernel<<<2 * NTOT / 4, 256, 0, stream>>>(x_bold, x_dti, pw_b, pb_b,
                                                  pw_d, pb_d, hb, hd);
    att_kernel<<<4 * BB, 1024, 0, stream>>>(ei_bb, ei_bd, ei_db, ei_dd,
                                            hb, hd, att, obuf);
    grp_reduce_kernel<<<4 * NTOT / 256, 256, 0, stream>>>(obuf, k_w, k_b, sums);
    grp_w_kernel<<<1, 64, 0, stream>>>(sums, qv, wscal);
    score_kernel<<<NTOT / 256, 256, 0, stream>>>(obuf, wscal, sb, sd,
                                                 out + O_SB, out + O_SD);
    topk_kernel<<<BB, 256, 0, stream>>>(sb, sd, batch_b, batch_d,
                                        mask_b, mask_d, perm_b, perm_d, out);
    gather_kernel<<<2 * BKK * 64 / 256, 256, 0, stream>>>(x_bold, x_dti,
                                                          perm_b, perm_d,
                                                          sb, sd, out);
    filter_kernel<<<EE / 256, 256, 0, stream>>>(ei_bb, ei_bd, ei_db, ei_dd,
                                                mask_b, mask_d, out);
}

// Round 2
// 921.124 us; speedup vs baseline: 1.0310x; 1.0310x over previous
//
#include <hip/hip_runtime.h>
#include <cmath>

// Problem constants (from reference)
#define BB   512                 // graphs
#define NN   246                 // nodes per graph per type
#define DD   256                 // feature dim
#define DEGC 32                  // edges per node
#define KK   197                 // kept nodes per graph (ceil(0.8*246))
#define NTOT (BB*NN)             // 125952
#define EE   (BB*NN*DEGC)        // 4030464 edges per edge type
#define EPG  (NN*DEGC)           // 7872 edges per graph
#define EPG4 (EPG/4)             // 1968
#define BKK  (BB*KK)             // 100864

// d_out element offsets (float32, concatenated reference outputs)
// xb[BK,D], xd[BK,D], {ei_f[2E], valid[E]} x4 (bb,bd,db,dd),
// batch_b[BK], batch_d[BK], perm_b[BK], perm_d[BK], s_bold[NT], s_dti[NT]
#define O_XB     0LL
#define O_XD     25821184LL
#define O_E0     51642368LL
#define STRIDE3E 12091392LL      // 3*EE per edge-type block
#define O_BATCHB 100007936LL
#define O_BATCHD 100108800LL
#define O_PERMB  100209664LL
#define O_PERMD  100310528LL
#define O_SB     100411392LL
#define O_SD     100537344LL
// total out elements = 100663296

// ============ 1. projection: h = x @ w + b  (scalar per node) ============
// one wave per node; 64 lanes x float4 = 256 floats; double accumulate.
// block 0 also zeroes the semantic-attention accumulators (consumed only
// after att_kernel, so no race).
__global__ __launch_bounds__(256) void proj_kernel(
    const float* __restrict__ xb, const float* __restrict__ xd,
    const float* __restrict__ wb, const float* __restrict__ bbp,
    const float* __restrict__ wd, const float* __restrict__ bdp,
    float* __restrict__ hb, float* __restrict__ hd,
    double* __restrict__ sums) {
    if (blockIdx.x == 0 && threadIdx.x < 4) sums[threadIdx.x] = 0.0;
    int wid  = (blockIdx.x * 256 + threadIdx.x) >> 6;
    int lane = threadIdx.x & 63;
    if (wid >= 2 * NTOT) return;
    const float* x; const float* w; const float* bp; float* h; int node;
    if (wid < NTOT) { x = xb; w = wb; bp = bbp; h = hb; node = wid; }
    else            { x = xd; w = wd; bp = bdp; h = hd; node = wid - NTOT; }
    float4 xv = ((const float4*)(x + (long long)node * DD))[lane];
    float4 wv = ((const float4*)w)[lane];
    double acc = (double)xv.x * wv.x + (double)xv.y * wv.y +
                 (double)xv.z * wv.z + (double)xv.w * wv.w;
#pragma unroll
    for (int m = 32; m; m >>= 1) acc += __shfl_xor(acc, m, 64);
    if (lane == 0) h[node] = __fadd_rn((float)acc, bp[0]);
}

// ============ 2. per-(graph, edge-type) attention, single pass ===========
// Softmax is shift-invariant: skip the per-dst max (reference subtracts it
// only for stability; logits here span ~[-18,18] so exp() stays in f32
// range). Per edge: e = exp(leaky_relu(a_src*h_s[r] + a_dst*h_d[c])),
// accumulate sum(e) and sum(h_s*e) per dst with LDS float atomics.
// h slices staged in LDS (984 B each); total LDS ~4 KB -> high occupancy.
__global__ __launch_bounds__(512) void att_kernel(
    const int* __restrict__ ei_bb, const int* __restrict__ ei_bd,
    const int* __restrict__ ei_db, const int* __restrict__ ei_dd,
    const float* __restrict__ hb, const float* __restrict__ hd,
    const float* __restrict__ att, float* __restrict__ o) {
    __shared__ float hs_sh[NN];   // src h slice
    __shared__ float hd_sh[NN];   // dst h slice
    __shared__ float s_sh[NN];    // sum(e)  (init 1e-16 to fold the epsilon)
    __shared__ float num_sh[NN];  // sum(h_src*e)

    int bid = blockIdx.x;
    int t   = bid >> 9;          // edge type 0..3 (bb, bd, db, dd)
    int g   = bid & 511;         // graph
    const int* ei = (t == 0) ? ei_bb : (t == 1) ? ei_bd : (t == 2) ? ei_db : ei_dd;
    const float* hs  = (t >= 2) ? hd : hb;   // src: bb,bd from bold; db,dd from dti
    const float* hdt = (t & 1)  ? hd : hb;   // dst: bd,dd to dti
    float a_src = att[2 * t], a_dst = att[2 * t + 1];
    int base = g * NN;
    int tid  = threadIdx.x;

    if (tid < NN) {
        hs_sh[tid]  = hs[base + tid];
        hd_sh[tid]  = hdt[base + tid];
        s_sh[tid]   = 1e-16f;
        num_sh[tid] = 0.f;
    }
    __syncthreads();

    const int4* rows = (const int4*)(ei + g * EPG);
    const int4* cols = (const int4*)(ei + EE + g * EPG);

    for (int q = tid; q < EPG4; q += 512) {
        int4 r4 = rows[q], c4 = cols[q];
#pragma unroll
        for (int j = 0; j < 4; ++j) {
            int r = ((const int*)&r4)[j] - base;
            int c = ((const int*)&c4)[j] - base;
            float hr = hs_sh[r];
            float l  = __fadd_rn(__fmul_rn(a_src, hr), __fmul_rn(a_dst, hd_sh[c]));
            l = (l >= 0.f) ? l : __fmul_rn(0.2f, l);   // leaky_relu 0.2
            float e = expf(l);
            atomicAdd(&s_sh[c], e);
            atomicAdd(&num_sh[c], __fmul_rn(hr, e));
        }
    }
    __syncthreads();

    if (tid < NN) {
        float v = num_sh[tid] / s_sh[tid];
        o[(long long)t * NTOT + base + tid] = (v > 0.f) ? v : 0.f;
    }
}

// ============ 3b. mean over NT of tanh(o*kw + kb), per edge type =========
__global__ __launch_bounds__(256) void grp_reduce_kernel(
    const float* __restrict__ o, const float* __restrict__ kwp,
    const float* __restrict__ kbp, double* __restrict__ sums) {
    int i = blockIdx.x * 256 + threadIdx.x;     // grid = 4*NT/256 = 1968
    int t = blockIdx.x / 492;                   // NT/256 = 492 blocks per type
    float kw = kwp[0], kb = kbp[0];
    float v = tanhf(__fadd_rn(__fmul_rn(o[i], kw), kb));
    double acc = (double)v;
#pragma unroll
    for (int m = 32; m; m >>= 1) acc += __shfl_xor(acc, m, 64);
    __shared__ double part[4];
    int lane = threadIdx.x & 63, wv = threadIdx.x >> 6;
    if (lane == 0) part[wv] = acc;
    __syncthreads();
    if (threadIdx.x == 0) {
        double tot = ((part[0] + part[1]) + part[2]) + part[3];
        atomicAdd(&sums[t], tot);
    }
}

// ============ 3c. semantic-attention weights (2-way softmax x 2) =========
__global__ void grp_w_kernel(const double* __restrict__ sums,
                             const float* __restrict__ qp,
                             float* __restrict__ wscal) {
    if (threadIdx.x == 0 && blockIdx.x == 0) {
        float q = qp[0];
        float tv[4];
#pragma unroll
        for (int i = 0; i < 4; ++i) tv[i] = (float)(sums[i] / (double)NTOT);
        // bold group: (o_bb = t0, o_db = t2)
        {
            float l0 = __fmul_rn(q, tv[0]), l1 = __fmul_rn(q, tv[2]);
            float mx = fmaxf(l0, l1);
            float e0 = expf(l0 - mx), e1 = expf(l1 - mx);
            float se = __fadd_rn(e0, e1);
            wscal[0] = e0 / se; wscal[1] = e1 / se;
        }
        // dti group: (o_bd = t1, o_dd = t3)
        {
            float l0 = __fmul_rn(q, tv[1]), l1 = __fmul_rn(q, tv[3]);
            float mx = fmaxf(l0, l1);
            float e0 = expf(l0 - mx), e1 = expf(l1 - mx);
            float se = __fadd_rn(e0, e1);
            wscal[2] = e0 / se; wscal[3] = e1 / se;
        }
    }
}

// ============ 3d. final scores; also written straight to d_out ===========
__global__ __launch_bounds__(256) void score_kernel(
    const float* __restrict__ o, const float* __restrict__ wscal,
    float* __restrict__ sb, float* __restrict__ sd,
    float* __restrict__ osb, float* __restrict__ osd) {
    int i = blockIdx.x * 256 + threadIdx.x;     // grid covers NT exactly
    float w0 = wscal[0], w1 = wscal[1], w2 = wscal[2], w3 = wscal[3];
    float vb = __fadd_rn(__fmul_rn(w0, o[i]),          __fmul_rn(w1, o[2LL * NTOT + i]));
    float vd = __fadd_rn(__fmul_rn(w2, o[NTOT + i]),   __fmul_rn(w3, o[3LL * NTOT + i]));
    sb[i] = vb; sd[i] = vd; osb[i] = vb; osd[i] = vd;
}

// ============ 4. per-graph top-K via bitonic sort (value desc, idx asc) ==
// replicates jax.lax.top_k incl. lower-index-first tie-break.
// grid = 2*BB: both node types in parallel.
__global__ __launch_bounds__(256) void topk_kernel(
    const float* __restrict__ sb, const float* __restrict__ sd,
    const int* __restrict__ batch_b, const int* __restrict__ batch_d,
    int* __restrict__ mask_b, int* __restrict__ mask_d,
    int* __restrict__ perm_b, int* __restrict__ perm_d,
    float* __restrict__ out) {
    __shared__ float v[256];
    __shared__ int   ix[256];
    int g = blockIdx.x & 511, which = blockIdx.x >> 9, tid = threadIdx.x;
    const float* s     = which ? sd : sb;
    const int*   batch = which ? batch_d : batch_b;
    int* mask  = which ? mask_d : mask_b;
    int* permi = which ? perm_d : perm_b;
    float* operm  = out + (which ? O_PERMD : O_PERMB);
    float* obatch = out + (which ? O_BATCHD : O_BATCHB);
    v[tid]  = (tid < NN) ? s[g * NN + tid] : -INFINITY;
    ix[tid] = tid;
    __syncthreads();
    for (int k2 = 2; k2 <= 256; k2 <<= 1) {
        for (int j = k2 >> 1; j > 0; j >>= 1) {
            int p = tid ^ j;
            if (p > tid) {
                float va = v[tid], vb2 = v[p];
                int   ia = ix[tid], ib = ix[p];
                bool before = (va > vb2) || (va == vb2 && ia < ib);
                bool up = ((tid & k2) == 0);
                if (up ? !before : before) {
                    v[tid] = vb2; v[p] = va; ix[tid] = ib; ix[p] = ia;
                }
            }
            __syncthreads();
        }
    }
    if (tid < NN) {
        int node  = ix[tid];
        int gnode = g * NN + node;
        if (tid < KK) {
            int gp = g * KK + tid;
            permi[gp]  = gnode;
            operm[gp]  = (float)gnode;
            obatch[gp] = (float)batch[gnode];
            mask[gnode] = gp;
        } else {
            mask[gnode] = -1;
        }
    }
}

// ============ 5. gather kept rows, scale by tanh(score) ==================
__global__ __launch_bounds__(256) void gather_kernel(
    const float* __restrict__ xb, const float* __restrict__ xd,
    const int* __restrict__ perm_b, const int* __restrict__ perm_d,
    const float* __restrict__ sb, const float* __restrict__ sd,
    float* __restrict__ out) {
    int wid  = (blockIdx.x * 256 + threadIdx.x) >> 6;
    int lane = threadIdx.x & 63;
    if (wid >= 2 * BKK) return;
    int which = wid >= BKK;
    int j = which ? wid - BKK : wid;
    const float* x    = which ? xd : xb;
    const int*   perm = which ? perm_d : perm_b;
    const float* s    = which ? sd : sb;
    long long obase   = which ? O_XD : O_XB;
    int p = perm[j];
    float scale = tanhf(s[p]);
    float4 vv = ((const float4*)(x + (long long)p * DD))[lane];
    float4 r  = make_float4(vv.x * scale, vv.y * scale, vv.z * scale, vv.w * scale);
    ((float4*)(out + obase + (long long)j * DD))[lane] = r;
}

// ============ 6. edge filtering through the pooling masks ================
__global__ __launch_bounds__(256) void filter_kernel(
    const int* __restrict__ ei_bb, const int* __restrict__ ei_bd,
    const int* __restrict__ ei_db, const int* __restrict__ ei_dd,
    const int* __restrict__ mask_b, const int* __restrict__ mask_d,
    float* __restrict__ out) {
    const int QE = EE / 4;
    int tid = blockIdx.x * 256 + threadIdx.x;
    if (tid >= 4 * QE) return;
    int t = tid / QE;
    int q = tid - t * QE;
    const int* ei = (t == 0) ? ei_bb : (t == 1) ? ei_bd : (t == 2) ? ei_db : ei_dd;
    const int* mr = (t >= 2) ? mask_d : mask_b;  // bb:(mb,mb) bd:(mb,md) db:(md,mb) dd:(md,md)
    const int* mc = (t & 1)  ? mask_d : mask_b;
    int4 r4 = ((const int4*)ei)[q];
    int4 c4 = ((const int4*)(ei + EE))[q];
    float4 orow, ocol, oval;
#pragma unroll
    for (int j = 0; j < 4; ++j) {
        int r = mr[((const int*)&r4)[j]];
        int c = mc[((const int*)&c4)[j]];
        bool val = (r >= 0) && (c >= 0);
        ((float*)&orow)[j] = val ? (float)r : -1.f;
        ((float*)&ocol)[j] = val ? (float)c : -1.f;
        ((float*)&oval)[j] = val ? 1.f : 0.f;
    }
    float* base = out + O_E0 + (long long)t * STRIDE3E;
    ((float4*)base)[q]              = orow;
    ((float4*)(base + EE))[q]       = ocol;
    ((float4*)(base + 2LL * EE))[q] = oval;
}

// ========================== launcher =====================================
extern "C" void kernel_launch(void* const* d_in, const int* in_sizes, int n_in,
                              void* d_out, int out_size, void* d_ws, size_t ws_size,
                              hipStream_t stream) {
    const float* x_bold = (const float*)d_in[0];
    const float* x_dti  = (const float*)d_in[1];
    const float* pw_b   = (const float*)d_in[2];
    const float* pb_b   = (const float*)d_in[3];
    const float* pw_d   = (const float*)d_in[4];
    const float* pb_d   = (const float*)d_in[5];
    const float* att    = (const float*)d_in[6];
    const float* k_w    = (const float*)d_in[7];
    const float* k_b    = (const float*)d_in[8];
    const float* qv     = (const float*)d_in[9];
    const int* ei_bb    = (const int*)d_in[10];
    const int* ei_bd    = (const int*)d_in[11];
    const int* ei_db    = (const int*)d_in[12];
    const int* ei_dd    = (const int*)d_in[13];
    const int* batch_b  = (const int*)d_in[14];
    const int* batch_d  = (const int*)d_in[15];
    float* out = (float*)d_out;

    // workspace layout (~5.9 MB)
    char* w = (char*)d_ws;
    double* sums  = (double*)w;                       // 4 dbl
    float*  wscal = (float*)(w + 32);                 // 4 f32
    float*  hb    = (float*)(w + 48);                 // NT
    float*  hd    = hb + NTOT;                        // NT
    float*  obuf  = hd + NTOT;                        // 4*NT
    float*  sb    = obuf + 4LL * NTOT;                // NT
    float*  sd    = sb + NTOT;                        // NT
    int* mask_b   = (int*)(sd + NTOT);                // NT
    int* mask_d   = mask_b + NTOT;                    // NT
    int* perm_b   = mask_d + NTOT;                    // BK
    int* perm_d   = perm_b + BKK;                     // BK

    proj_kernel<<<2 * NTOT / 4, 256, 0, stream>>>(x_bold, x_dti, pw_b, pb_b,
                                                  pw_d, pb_d, hb, hd, sums);
    att_kernel<<<4 * BB, 512, 0, stream>>>(ei_bb, ei_bd, ei_db, ei_dd,
                                           hb, hd, att, obuf);
    grp_reduce_kernel<<<4 * NTOT / 256, 256, 0, stream>>>(obuf, k_w, k_b, sums);
    grp_w_kernel<<<1, 64, 0, stream>>>(sums, qv, wscal);
    score_kernel<<<NTOT / 256, 256, 0, stream>>>(obuf, wscal, sb, sd,
                                                 out + O_SB, out + O_SD);
    topk_kernel<<<2 * BB, 256, 0, stream>>>(sb, sd, batch_b, batch_d,
                                            mask_b, mask_d, perm_b, perm_d, out);
    gather_kernel<<<2 * BKK * 64 / 256, 256, 0, stream>>>(x_bold, x_dti,
                                                          perm_b, perm_d,
                                                          sb, sd, out);
    filter_kernel<<<EE / 256, 256, 0, stream>>>(ei_bb, ei_bd, ei_db, ei_dd,
                                                mask_b, mask_d, out);
}

// Round 4
// 880.837 us; speedup vs baseline: 1.0782x; 1.0457x over previous
//
#include <hip/hip_runtime.h>
#include <cmath>

// Problem constants (from reference)
#define BB   512                 // graphs
#define NN   246                 // nodes per graph per type
#define DD   256                 // feature dim
#define DEGC 32                  // edges per node
#define KK   197                 // kept nodes per graph (ceil(0.8*246))
#define NTOT (BB*NN)             // 125952
#define EE   (BB*NN*DEGC)        // 4030464 edges per edge type
#define EPG  (NN*DEGC)           // 7872 edges per graph
#define EPG4 (EPG/4)             // 1968
#define BKK  (BB*KK)             // 100864

// d_out element offsets (float32, concatenated reference outputs)
#define O_XB     0LL
#define O_XD     25821184LL
#define O_E0     51642368LL
#define STRIDE3E 12091392LL      // 3*EE per edge-type block
#define O_BATCHB 100007936LL
#define O_BATCHD 100108800LL
#define O_PERMB  100209664LL
#define O_PERMD  100310528LL
#define O_SB     100411392LL
#define O_SD     100537344LL
// total out elements = 100663296

// native clang vector types — __builtin_nontemporal_* requires these
// (HIP_vector_type float4/int4 are rejected; layout is identical)
typedef float vf4 __attribute__((ext_vector_type(4)));
typedef int   vi4 __attribute__((ext_vector_type(4)));

__device__ __forceinline__ vi4 nt_load_i4(const int* p) {
    return __builtin_nontemporal_load((const vi4*)p);
}
__device__ __forceinline__ vf4 nt_load_f4(const float* p) {
    return __builtin_nontemporal_load((const vf4*)p);
}
__device__ __forceinline__ void nt_store_f4(float* p, vf4 v) {
    __builtin_nontemporal_store(v, (vf4*)p);
}
__device__ __forceinline__ void nt_store_f(float* p, float v) {
    __builtin_nontemporal_store(v, p);
}

// ============ 1. projection: h = x @ w + b  (scalar per node) ============
// one wave per node; 64 lanes x float4 = 256 floats; double accumulate.
// block 0 also zeroes the 4 semantic-attention accumulators.
__global__ __launch_bounds__(256) void proj_kernel(
    const float* __restrict__ xb, const float* __restrict__ xd,
    const float* __restrict__ wb, const float* __restrict__ bbp,
    const float* __restrict__ wd, const float* __restrict__ bdp,
    float* __restrict__ hb, float* __restrict__ hd,
    double* __restrict__ sums) {
    if (blockIdx.x == 0 && threadIdx.x < 4) sums[threadIdx.x] = 0.0;
    int wid  = (blockIdx.x * 256 + threadIdx.x) >> 6;
    int lane = threadIdx.x & 63;
    if (wid >= 2 * NTOT) return;
    const float* x; const float* w; const float* bp; float* h; int node;
    if (wid < NTOT) { x = xb; w = wb; bp = bbp; h = hb; node = wid; }
    else            { x = xd; w = wd; bp = bdp; h = hd; node = wid - NTOT; }
    vf4 xv = nt_load_f4(x + (long long)node * DD + 4 * lane);
    vf4 wv = *(const vf4*)(w + 4 * lane);
    double acc = (double)xv.x * wv.x + (double)xv.y * wv.y +
                 (double)xv.z * wv.z + (double)xv.w * wv.w;
#pragma unroll
    for (int m = 32; m; m >>= 1) acc += __shfl_xor(acc, m, 64);
    if (lane == 0) h[node] = __fadd_rn((float)acc, bp[0]);
}

// ============ 2. per-(graph, edge-type) attention, single pass ===========
// e = exp(leaky_relu(a_src*h_s[r] + a_dst*h_d[c])) accumulated per dst via
// LDS float atomics (softmax shift-invariance: max-subtraction dropped;
// logits span ~±18, safe in f32). Also computes this block's partial
// sum of tanh(o*kw+kb) for the semantic attention -> one f64 atomicAdd.
__global__ __launch_bounds__(512) void att_kernel(
    const int* __restrict__ ei_bb, const int* __restrict__ ei_bd,
    const int* __restrict__ ei_db, const int* __restrict__ ei_dd,
    const float* __restrict__ hb, const float* __restrict__ hd,
    const float* __restrict__ att, const float* __restrict__ kwp,
    const float* __restrict__ kbp, float* __restrict__ o,
    double* __restrict__ sums) {
    __shared__ float hs_sh[NN];   // src h slice
    __shared__ float hd_sh[NN];   // dst h slice
    __shared__ float s_sh[NN];    // sum(e)  (init 1e-16 folds the epsilon)
    __shared__ float num_sh[NN];  // sum(h_src*e)
    __shared__ double part[8];

    int bid = blockIdx.x;
    int t   = bid >> 9;          // edge type 0..3 (bb, bd, db, dd)
    int g   = bid & 511;         // graph
    const int* ei = (t == 0) ? ei_bb : (t == 1) ? ei_bd : (t == 2) ? ei_db : ei_dd;
    const float* hs  = (t >= 2) ? hd : hb;   // src: bb,bd from bold; db,dd from dti
    const float* hdt = (t & 1)  ? hd : hb;   // dst: bd,dd to dti
    float a_src = att[2 * t], a_dst = att[2 * t + 1];
    int base = g * NN;
    int tid  = threadIdx.x;

    if (tid < NN) {
        hs_sh[tid]  = hs[base + tid];
        hd_sh[tid]  = hdt[base + tid];
        s_sh[tid]   = 1e-16f;
        num_sh[tid] = 0.f;
    }
    __syncthreads();

    const int* rows = ei + g * EPG;
    const int* cols = ei + EE + g * EPG;

    for (int q = tid; q < EPG4; q += 512) {
        vi4 r4 = nt_load_i4(rows + 4 * q);
        vi4 c4 = nt_load_i4(cols + 4 * q);
#pragma unroll
        for (int j = 0; j < 4; ++j) {
            int r = r4[j] - base;
            int c = c4[j] - base;
            float hr = hs_sh[r];
            float l  = __fadd_rn(__fmul_rn(a_src, hr), __fmul_rn(a_dst, hd_sh[c]));
            l = (l >= 0.f) ? l : __fmul_rn(0.2f, l);   // leaky_relu 0.2
            float e = expf(l);
            atomicAdd(&s_sh[c], e);
            atomicAdd(&num_sh[c], __fmul_rn(hr, e));
        }
    }
    __syncthreads();

    float kw = kwp[0], kb = kbp[0];
    float my = 0.f;
    if (tid < NN) {
        float v = num_sh[tid] / s_sh[tid];
        v = (v > 0.f) ? v : 0.f;
        o[(long long)t * NTOT + base + tid] = v;
        my = tanhf(__fadd_rn(__fmul_rn(v, kw), kb));
    }
    // block-reduce tanh partial (threads >= NN contribute 0)
    double acc = (double)my;
#pragma unroll
    for (int m = 32; m; m >>= 1) acc += __shfl_xor(acc, m, 64);
    int lane = tid & 63, wv = tid >> 6;
    if (lane == 0) part[wv] = acc;
    __syncthreads();
    if (tid == 0) {
        double tot = 0.0;
#pragma unroll
        for (int i = 0; i < 8; ++i) tot += part[i];
        atomicAdd(&sums[t], tot);
    }
}

// ======== 3. final scores (semantic softmax computed inline) =============
__global__ __launch_bounds__(256) void score_kernel(
    const float* __restrict__ o, const double* __restrict__ sums,
    const float* __restrict__ qp,
    float* __restrict__ sb, float* __restrict__ sd,
    float* __restrict__ osb, float* __restrict__ osd) {
    int i = blockIdx.x * 256 + threadIdx.x;     // grid covers NT exactly
    float q = qp[0];
    float t0 = (float)(sums[0] / (double)NTOT);
    float t1 = (float)(sums[1] / (double)NTOT);
    float t2 = (float)(sums[2] / (double)NTOT);
    float t3 = (float)(sums[3] / (double)NTOT);
    // bold group: (o_bb = t0, o_db = t2)
    float l0 = __fmul_rn(q, t0), l1 = __fmul_rn(q, t2);
    float mx = fmaxf(l0, l1);
    float e0 = expf(l0 - mx), e1 = expf(l1 - mx);
    float se = __fadd_rn(e0, e1);
    float w0 = e0 / se, w1 = e1 / se;
    // dti group: (o_bd = t1, o_dd = t3)
    float l2 = __fmul_rn(q, t1), l3 = __fmul_rn(q, t3);
    float mx2 = fmaxf(l2, l3);
    float e2 = expf(l2 - mx2), e3 = expf(l3 - mx2);
    float se2 = __fadd_rn(e2, e3);
    float w2 = e2 / se2, w3 = e3 / se2;
    float vb = __fadd_rn(__fmul_rn(w0, o[i]),        __fmul_rn(w1, o[2LL * NTOT + i]));
    float vd = __fadd_rn(__fmul_rn(w2, o[NTOT + i]), __fmul_rn(w3, o[3LL * NTOT + i]));
    sb[i] = vb; sd[i] = vd;
    nt_store_f(osb + i, vb); nt_store_f(osd + i, vd);
}

// ============ 4. per-graph top-K via O(N^2) rank (barrier-light) =========
// rank = #{j: v_j > v_t  or  (v_j == v_t and j < t)} — exactly
// jax.lax.top_k's order (desc value, lower index first on ties).
__global__ __launch_bounds__(256) void topk_kernel(
    const float* __restrict__ sb, const float* __restrict__ sd,
    const int* __restrict__ batch_b, const int* __restrict__ batch_d,
    int* __restrict__ mask_b, int* __restrict__ mask_d,
    int* __restrict__ perm_b, int* __restrict__ perm_d,
    float* __restrict__ out) {
    __shared__ float v[NN];
    int g = blockIdx.x & 511, which = blockIdx.x >> 9, tid = threadIdx.x;
    const float* s     = which ? sd : sb;
    const int*   batch = which ? batch_d : batch_b;
    int* mask  = which ? mask_d : mask_b;
    int* permi = which ? perm_d : perm_b;
    float* operm  = out + (which ? O_PERMD : O_PERMB);
    float* obatch = out + (which ? O_BATCHD : O_BATCHB);
    if (tid < NN) v[tid] = s[g * NN + tid];
    __syncthreads();
    if (tid < NN) {
        float mv = v[tid];
        int rank = 0;
#pragma unroll 4
        for (int j = 0; j < NN; ++j) {
            float vj = v[j];
            rank += (vj > mv) || (vj == mv && j < tid);
        }
        int gnode = g * NN + tid;
        if (rank < KK) {
            int gp = g * KK + rank;
            permi[gp] = gnode;
            nt_store_f(operm + gp, (float)gnode);
            nt_store_f(obatch + gp, (float)batch[gnode]);
            mask[gnode] = gp;
        } else {
            mask[gnode] = -1;
        }
    }
}

// ============ 5. gather kept rows, scale by tanh(score) ==================
__global__ __launch_bounds__(256) void gather_kernel(
    const float* __restrict__ xb, const float* __restrict__ xd,
    const int* __restrict__ perm_b, const int* __restrict__ perm_d,
    const float* __restrict__ sb, const float* __restrict__ sd,
    float* __restrict__ out) {
    int wid  = (blockIdx.x * 256 + threadIdx.x) >> 6;
    int lane = threadIdx.x & 63;
    if (wid >= 2 * BKK) return;
    int which = wid >= BKK;
    int j = which ? wid - BKK : wid;
    const float* x    = which ? xd : xb;
    const int*   perm = which ? perm_d : perm_b;
    const float* s    = which ? sd : sb;
    long long obase   = which ? O_XD : O_XB;
    int p = perm[j];
    float scale = tanhf(s[p]);
    vf4 vv = nt_load_f4(x + (long long)p * DD + 4 * lane);
    vf4 r;
    r.x = vv.x * scale; r.y = vv.y * scale;
    r.z = vv.z * scale; r.w = vv.w * scale;
    nt_store_f4(out + obase + (long long)j * DD + 4 * lane, r);
}

// ============ 6. edge filtering through the pooling masks ================
__global__ __launch_bounds__(256) void filter_kernel(
    const int* __restrict__ ei_bb, const int* __restrict__ ei_bd,
    const int* __restrict__ ei_db, const int* __restrict__ ei_dd,
    const int* __restrict__ mask_b, const int* __restrict__ mask_d,
    float* __restrict__ out) {
    const int QE = EE / 4;
    int tid = blockIdx.x * 256 + threadIdx.x;
    if (tid >= 4 * QE) return;
    int t = tid / QE;
    int q = tid - t * QE;
    const int* ei = (t == 0) ? ei_bb : (t == 1) ? ei_bd : (t == 2) ? ei_db : ei_dd;
    const int* mr = (t >= 2) ? mask_d : mask_b;  // bb:(mb,mb) bd:(mb,md) db:(md,mb) dd:(md,md)
    const int* mc = (t & 1)  ? mask_d : mask_b;
    vi4 r4 = nt_load_i4(ei + 4 * q);
    vi4 c4 = nt_load_i4(ei + EE + 4 * q);
    vf4 orow, ocol, oval;
#pragma unroll
    for (int j = 0; j < 4; ++j) {
        int r = mr[r4[j]];
        int c = mc[c4[j]];
        bool val = (r >= 0) && (c >= 0);
        orow[j] = val ? (float)r : -1.f;
        ocol[j] = val ? (float)c : -1.f;
        oval[j] = val ? 1.f : 0.f;
    }
    float* base = out + O_E0 + (long long)t * STRIDE3E;
    nt_store_f4(base + 4 * q,              orow);
    nt_store_f4(base + EE + 4 * q,         ocol);
    nt_store_f4(base + 2LL * EE + 4 * q,   oval);
}

// ========================== launcher =====================================
extern "C" void kernel_launch(void* const* d_in, const int* in_sizes, int n_in,
                              void* d_out, int out_size, void* d_ws, size_t ws_size,
                              hipStream_t stream) {
    const float* x_bold = (const float*)d_in[0];
    const float* x_dti  = (const float*)d_in[1];
    const float* pw_b   = (const float*)d_in[2];
    const float* pb_b   = (const float*)d_in[3];
    const float* pw_d   = (const float*)d_in[4];
    const float* pb_d   = (const float*)d_in[5];
    const float* att    = (const float*)d_in[6];
    const float* k_w    = (const float*)d_in[7];
    const float* k_b    = (const float*)d_in[8];
    const float* qv     = (const float*)d_in[9];
    const int* ei_bb    = (const int*)d_in[10];
    const int* ei_bd    = (const int*)d_in[11];
    const int* ei_db    = (const int*)d_in[12];
    const int* ei_dd    = (const int*)d_in[13];
    const int* batch_b  = (const int*)d_in[14];
    const int* batch_d  = (const int*)d_in[15];
    float* out = (float*)d_out;

    // workspace layout (~5.9 MB)
    char* w = (char*)d_ws;
    double* sums  = (double*)w;                       // 4 dbl
    float*  hb    = (float*)(w + 64);                 // NT
    float*  hd    = hb + NTOT;                        // NT
    float*  obuf  = hd + NTOT;                        // 4*NT
    float*  sb    = obuf + 4LL * NTOT;                // NT
    float*  sd    = sb + NTOT;                        // NT
    int* mask_b   = (int*)(sd + NTOT);                // NT
    int* mask_d   = mask_b + NTOT;                    // NT
    int* perm_b   = mask_d + NTOT;                    // BK
    int* perm_d   = perm_b + BKK;                     // BK

    proj_kernel<<<2 * NTOT / 4, 256, 0, stream>>>(x_bold, x_dti, pw_b, pb_b,
                                                  pw_d, pb_d, hb, hd, sums);
    att_kernel<<<4 * BB, 512, 0, stream>>>(ei_bb, ei_bd, ei_db, ei_dd,
                                           hb, hd, att, k_w, k_b, obuf, sums);
    score_kernel<<<NTOT / 256, 256, 0, stream>>>(obuf, sums, qv, sb, sd,
                                                 out + O_SB, out + O_SD);
    topk_kernel<<<2 * BB, 256, 0, stream>>>(sb, sd, batch_b, batch_d,
                                            mask_b, mask_d, perm_b, perm_d, out);
    gather_kernel<<<2 * BKK * 64 / 256, 256, 0, stream>>>(x_bold, x_dti,
                                                          perm_b, perm_d,
                                                          sb, sd, out);
    filter_kernel<<<EE / 256, 256, 0, stream>>>(ei_bb, ei_bd, ei_db, ei_dd,
                                                mask_b, mask_d, out);
}

// Round 5
// 876.754 us; speedup vs baseline: 1.0832x; 1.0047x over previous
//
#include <hip/hip_runtime.h>
#include <cmath>

// Problem constants (from reference)
#define BB   512                 // graphs
#define NN   246                 // nodes per graph per type
#define DD   256                 // feature dim
#define DEGC 32                  // edges per node
#define KK   197                 // kept nodes per graph (ceil(0.8*246))
#define NTOT (BB*NN)             // 125952
#define EE   (BB*NN*DEGC)        // 4030464 edges per edge type
#define EPG  (NN*DEGC)           // 7872 edges per graph
#define EPG4 (EPG/4)             // 1968
#define BKK  (BB*KK)             // 100864

// d_out element offsets (float32, concatenated reference outputs)
#define O_XB     0LL
#define O_XD     25821184LL
#define O_E0     51642368LL
#define STRIDE3E 12091392LL      // 3*EE per edge-type block
#define O_BATCHB 100007936LL
#define O_BATCHD 100108800LL
#define O_PERMB  100209664LL
#define O_PERMD  100310528LL
#define O_SB     100411392LL
#define O_SD     100537344LL
// total out elements = 100663296

// epilogue grid split: gather blocks (512 thr = 8 waves = 8 rows), then
// filter blocks (one per (graph, edge-type))
#define GATH_BLOCKS (2*BKK/8)    // 25216
#define FILT_BLOCKS (4*BB)       // 2048

// native clang vector types — __builtin_nontemporal_* requires these
typedef float vf4 __attribute__((ext_vector_type(4)));
typedef int   vi4 __attribute__((ext_vector_type(4)));

__device__ __forceinline__ vi4 nt_load_i4(const int* p) {
    return __builtin_nontemporal_load((const vi4*)p);
}
__device__ __forceinline__ vf4 nt_load_f4(const float* p) {
    return __builtin_nontemporal_load((const vf4*)p);
}
__device__ __forceinline__ void nt_store_f4(float* p, vf4 v) {
    __builtin_nontemporal_store(v, (vf4*)p);
}
__device__ __forceinline__ void nt_store_f(float* p, float v) {
    __builtin_nontemporal_store(v, p);
}

// ============ 1. projection: h = x @ w + b  (scalar per node) ============
// one wave per node; 64 lanes x float4 = 256 floats; double accumulate.
// block 0 also zeroes the 4 semantic-attention accumulators.
__global__ __launch_bounds__(256) void proj_kernel(
    const float* __restrict__ xb, const float* __restrict__ xd,
    const float* __restrict__ wb, const float* __restrict__ bbp,
    const float* __restrict__ wd, const float* __restrict__ bdp,
    float* __restrict__ hb, float* __restrict__ hd,
    double* __restrict__ sums) {
    if (blockIdx.x == 0 && threadIdx.x < 4) sums[threadIdx.x] = 0.0;
    int wid  = (blockIdx.x * 256 + threadIdx.x) >> 6;
    int lane = threadIdx.x & 63;
    if (wid >= 2 * NTOT) return;
    const float* x; const float* w; const float* bp; float* h; int node;
    if (wid < NTOT) { x = xb; w = wb; bp = bbp; h = hb; node = wid; }
    else            { x = xd; w = wd; bp = bdp; h = hd; node = wid - NTOT; }
    vf4 xv = nt_load_f4(x + (long long)node * DD + 4 * lane);
    vf4 wv = *(const vf4*)(w + 4 * lane);
    double acc = (double)xv.x * wv.x + (double)xv.y * wv.y +
                 (double)xv.z * wv.z + (double)xv.w * wv.w;
#pragma unroll
    for (int m = 32; m; m >>= 1) acc += __shfl_xor(acc, m, 64);
    if (lane == 0) h[node] = __fadd_rn((float)acc, bp[0]);
}

// ============ 2. per-(graph, edge-type) attention, single pass ===========
// e = exp(leaky_relu(a_src*h_s[r] + a_dst*h_d[c])) accumulated per dst via
// LDS float atomics. 4 replica accumulators (tid&3) cut same-address
// collisions ~4x. Softmax max-subtraction dropped (shift-invariant; logits
// span ~±18, safe in f32). Also emits this block's partial sum of
// tanh(o*kw+kb) for the semantic attention -> one f64 atomicAdd.
__global__ __launch_bounds__(512) void att_kernel(
    const int* __restrict__ ei_bb, const int* __restrict__ ei_bd,
    const int* __restrict__ ei_db, const int* __restrict__ ei_dd,
    const float* __restrict__ hb, const float* __restrict__ hd,
    const float* __restrict__ att, const float* __restrict__ kwp,
    const float* __restrict__ kbp, float* __restrict__ o,
    double* __restrict__ sums) {
    __shared__ float hs_sh[NN];      // src h slice
    __shared__ float hd_sh[NN];      // dst h slice
    __shared__ float s_sh[4][NN];    // sum(e) replicas (replica 0 seeds 1e-16)
    __shared__ float num_sh[4][NN];  // sum(h_src*e) replicas
    __shared__ double part[8];

    int bid = blockIdx.x;
    int t   = bid >> 9;          // edge type 0..3 (bb, bd, db, dd)
    int g   = bid & 511;         // graph
    const int* ei = (t == 0) ? ei_bb : (t == 1) ? ei_bd : (t == 2) ? ei_db : ei_dd;
    const float* hs  = (t >= 2) ? hd : hb;   // src: bb,bd from bold; db,dd from dti
    const float* hdt = (t & 1)  ? hd : hb;   // dst: bd,dd to dti
    float a_src = att[2 * t], a_dst = att[2 * t + 1];
    int base = g * NN;
    int tid  = threadIdx.x;

    if (tid < NN) {
        hs_sh[tid]  = hs[base + tid];
        hd_sh[tid]  = hdt[base + tid];
        s_sh[0][tid] = 1e-16f; s_sh[1][tid] = 0.f;
        s_sh[2][tid] = 0.f;    s_sh[3][tid] = 0.f;
        num_sh[0][tid] = 0.f;  num_sh[1][tid] = 0.f;
        num_sh[2][tid] = 0.f;  num_sh[3][tid] = 0.f;
    }
    __syncthreads();

    const int* rows = ei + g * EPG;
    const int* cols = ei + EE + g * EPG;
    int rep = tid & 3;

    for (int q = tid; q < EPG4; q += 512) {
        vi4 r4 = nt_load_i4(rows + 4 * q);
        vi4 c4 = nt_load_i4(cols + 4 * q);
#pragma unroll
        for (int j = 0; j < 4; ++j) {
            int r = r4[j] - base;
            int c = c4[j] - base;
            float hr = hs_sh[r];
            float l  = __fadd_rn(__fmul_rn(a_src, hr), __fmul_rn(a_dst, hd_sh[c]));
            l = (l >= 0.f) ? l : __fmul_rn(0.2f, l);   // leaky_relu 0.2
            float e = __expf(l);
            atomicAdd(&s_sh[rep][c], e);
            atomicAdd(&num_sh[rep][c], __fmul_rn(hr, e));
        }
    }
    __syncthreads();

    float kw = kwp[0], kb = kbp[0];
    float my = 0.f;
    if (tid < NN) {
        float s = ((s_sh[0][tid] + s_sh[1][tid]) + (s_sh[2][tid] + s_sh[3][tid]));
        float n = ((num_sh[0][tid] + num_sh[1][tid]) + (num_sh[2][tid] + num_sh[3][tid]));
        float v = n / s;
        v = (v > 0.f) ? v : 0.f;
        o[(long long)t * NTOT + base + tid] = v;
        my = tanhf(__fadd_rn(__fmul_rn(v, kw), kb));
    }
    // block-reduce tanh partial (threads >= NN contribute 0)
    double acc = (double)my;
#pragma unroll
    for (int m = 32; m; m >>= 1) acc += __shfl_xor(acc, m, 64);
    int lane = tid & 63, wv = tid >> 6;
    if (lane == 0) part[wv] = acc;
    __syncthreads();
    if (tid == 0) {
        double tot = 0.0;
#pragma unroll
        for (int i = 0; i < 8; ++i) tot += part[i];
        atomicAdd(&sums[t], tot);
    }
}

// ======= 3. scores (semantic softmax inline) + per-graph top-K ===========
// one block per (graph, node-type); scores computed in-register, written to
// d_out, then O(N^2) stable rank: rank = #{j: v_j > v_t or (== and j < t)}
// — exactly jax.lax.top_k's order.
__global__ __launch_bounds__(256) void score_topk_kernel(
    const float* __restrict__ o, const double* __restrict__ sums,
    const float* __restrict__ qp,
    const int* __restrict__ batch_b, const int* __restrict__ batch_d,
    int* __restrict__ mask_b, int* __restrict__ mask_d,
    int* __restrict__ perm_b, int* __restrict__ perm_d,
    float* __restrict__ out) {
    __shared__ float v[NN];
    int g = blockIdx.x & 511, which = blockIdx.x >> 9, tid = threadIdx.x;
    float q = qp[0];
    float t0 = (float)(sums[0] / (double)NTOT);
    float t1 = (float)(sums[1] / (double)NTOT);
    float t2 = (float)(sums[2] / (double)NTOT);
    float t3 = (float)(sums[3] / (double)NTOT);
    float wA, wB;
    if (!which) {   // bold group: (o_bb = t0, o_db = t2)
        float l0 = __fmul_rn(q, t0), l1 = __fmul_rn(q, t2);
        float mx = fmaxf(l0, l1);
        float e0 = expf(l0 - mx), e1 = expf(l1 - mx);
        float se = __fadd_rn(e0, e1);
        wA = e0 / se; wB = e1 / se;
    } else {        // dti group: (o_bd = t1, o_dd = t3)
        float l0 = __fmul_rn(q, t1), l1 = __fmul_rn(q, t3);
        float mx = fmaxf(l0, l1);
        float e0 = expf(l0 - mx), e1 = expf(l1 - mx);
        float se = __fadd_rn(e0, e1);
        wA = e0 / se; wB = e1 / se;
    }
    const int* batch = which ? batch_d : batch_b;
    int* mask  = which ? mask_d : mask_b;
    int* permi = which ? perm_d : perm_b;
    float* operm  = out + (which ? O_PERMD : O_PERMB);
    float* obatch = out + (which ? O_BATCHD : O_BATCHB);
    float* oscore = out + (which ? O_SD : O_SB);

    if (tid < NN) {
        int i = g * NN + tid;
        float oA = which ? o[NTOT + i] : o[i];
        float oB = which ? o[3LL * NTOT + i] : o[2LL * NTOT + i];
        float val = __fadd_rn(__fmul_rn(wA, oA), __fmul_rn(wB, oB));
        v[tid] = val;
        nt_store_f(oscore + i, val);
    }
    __syncthreads();
    if (tid < NN) {
        float mv = v[tid];
        int rank = 0;
#pragma unroll 4
        for (int j = 0; j < NN; ++j) {
            float vj = v[j];
            rank += (vj > mv) || (vj == mv && j < tid);
        }
        int gnode = g * NN + tid;
        if (rank < KK) {
            int gp = g * KK + rank;
            permi[gp] = gnode;
            nt_store_f(operm + gp, (float)gnode);
            nt_store_f(obatch + gp, (float)batch[gnode]);
            mask[gnode] = gp;
        } else {
            mask[gnode] = -1;
        }
    }
}

// ====== 4. epilogue: gather (kept rows * tanh(score)) + edge filter ======
// blocks [0, GATH_BLOCKS): 8 output rows each (wave per row).
// blocks [GATH_BLOCKS, +FILT_BLOCKS): one (graph, edge-type) each; the two
// 246-entry mask slices are staged in LDS so per-edge lookups are LDS
// broadcasts instead of 32M uncoalesced L2 gathers.
__global__ __launch_bounds__(512) void epilogue_kernel(
    const float* __restrict__ xb, const float* __restrict__ xd,
    const int* __restrict__ perm_b, const int* __restrict__ perm_d,
    const int* __restrict__ ei_bb, const int* __restrict__ ei_bd,
    const int* __restrict__ ei_db, const int* __restrict__ ei_dd,
    const int* __restrict__ mask_b, const int* __restrict__ mask_d,
    float* __restrict__ out) {
    int b = blockIdx.x, tid = threadIdx.x;
    if (b < GATH_BLOCKS) {
        // ---------------- gather ----------------
        int wid  = (b * 512 + tid) >> 6;       // global row id, < 2*BKK exact
        int lane = tid & 63;
        int which = wid >= BKK;
        int j = which ? wid - BKK : wid;
        const float* x    = which ? xd : xb;
        const int*   perm = which ? perm_d : perm_b;
        const float* s    = out + (which ? O_SD : O_SB);
        long long obase   = which ? O_XD : O_XB;
        int p = perm[j];
        float scale = tanhf(s[p]);
        vf4 vv = nt_load_f4(x + (long long)p * DD + 4 * lane);
        vf4 r;
        r.x = vv.x * scale; r.y = vv.y * scale;
        r.z = vv.z * scale; r.w = vv.w * scale;
        nt_store_f4(out + obase + (long long)j * DD + 4 * lane, r);
    } else {
        // ---------------- filter ----------------
        __shared__ int mr_sh[NN];
        __shared__ int mc_sh[NN];
        int fb = b - GATH_BLOCKS;
        int t  = fb >> 9;                      // edge type
        int g  = fb & 511;                     // graph
        const int* ei = (t == 0) ? ei_bb : (t == 1) ? ei_bd : (t == 2) ? ei_db : ei_dd;
        const int* mr = (t >= 2) ? mask_d : mask_b;
        const int* mc = (t & 1)  ? mask_d : mask_b;
        int base = g * NN;
        if (tid < NN) {
            mr_sh[tid] = mr[base + tid];
            mc_sh[tid] = mc[base + tid];
        }
        __syncthreads();
        const int* rows = ei + g * EPG;
        const int* cols = ei + EE + g * EPG;
        float* obase = out + O_E0 + (long long)t * STRIDE3E + g * EPG;
        for (int q = tid; q < EPG4; q += 512) {
            vi4 r4 = nt_load_i4(rows + 4 * q);
            vi4 c4 = nt_load_i4(cols + 4 * q);
            vf4 orow, ocol, oval;
#pragma unroll
            for (int j = 0; j < 4; ++j) {
                int r = mr_sh[r4[j] - base];
                int c = mc_sh[c4[j] - base];
                bool val = (r >= 0) && (c >= 0);
                orow[j] = val ? (float)r : -1.f;
                ocol[j] = val ? (float)c : -1.f;
                oval[j] = val ? 1.f : 0.f;
            }
            nt_store_f4(obase + 4 * q,            orow);
            nt_store_f4(obase + EE + 4 * q,       ocol);
            nt_store_f4(obase + 2LL * EE + 4 * q, oval);
        }
    }
}

// ========================== launcher =====================================
extern "C" void kernel_launch(void* const* d_in, const int* in_sizes, int n_in,
                              void* d_out, int out_size, void* d_ws, size_t ws_size,
                              hipStream_t stream) {
    const float* x_bold = (const float*)d_in[0];
    const float* x_dti  = (const float*)d_in[1];
    const float* pw_b   = (const float*)d_in[2];
    const float* pb_b   = (const float*)d_in[3];
    const float* pw_d   = (const float*)d_in[4];
    const float* pb_d   = (const float*)d_in[5];
    const float* att    = (const float*)d_in[6];
    const float* k_w    = (const float*)d_in[7];
    const float* k_b    = (const float*)d_in[8];
    const float* qv     = (const float*)d_in[9];
    const int* ei_bb    = (const int*)d_in[10];
    const int* ei_bd    = (const int*)d_in[11];
    const int* ei_db    = (const int*)d_in[12];
    const int* ei_dd    = (const int*)d_in[13];
    const int* batch_b  = (const int*)d_in[14];
    const int* batch_d  = (const int*)d_in[15];
    float* out = (float*)d_out;

    // workspace layout (~4 MB)
    char* w = (char*)d_ws;
    double* sums  = (double*)w;                       // 4 dbl
    float*  hb    = (float*)(w + 64);                 // NT
    float*  hd    = hb + NTOT;                        // NT
    float*  obuf  = hd + NTOT;                        // 4*NT
    int* mask_b   = (int*)(obuf + 4LL * NTOT);        // NT
    int* mask_d   = mask_b + NTOT;                    // NT
    int* perm_b   = mask_d + NTOT;                    // BK
    int* perm_d   = perm_b + BKK;                     // BK

    proj_kernel<<<2 * NTOT / 4, 256, 0, stream>>>(x_bold, x_dti, pw_b, pb_b,
                                                  pw_d, pb_d, hb, hd, sums);
    att_kernel<<<4 * BB, 512, 0, stream>>>(ei_bb, ei_bd, ei_db, ei_dd,
                                           hb, hd, att, k_w, k_b, obuf, sums);
    score_topk_kernel<<<2 * BB, 256, 0, stream>>>(obuf, sums, qv,
                                                  batch_b, batch_d,
                                                  mask_b, mask_d,
                                                  perm_b, perm_d, out);
    epilogue_kernel<<<GATH_BLOCKS + FILT_BLOCKS, 512, 0, stream>>>(
        x_bold, x_dti, perm_b, perm_d,
        ei_bb, ei_bd, ei_db, ei_dd, mask_b, mask_d, out);
}